// Round 1
// baseline (265.362 us; speedup 1.0000x reference)
//
#include <hip/hip_runtime.h>
#include <math.h>

constexpr int B = 8, N = 2048, H = 512, A = 128;

// ---------------- K1: Qw/Kw projections + per-token gate ----------------
// 32 rows per WG, 256 threads. Thread t computes column a = t&127 of BOTH
// Qw and Kw for 16 rows (row-half = t>>7). x staged in LDS (64 KB).
__global__ __launch_bounds__(256) void k1_proj(
    const float* __restrict__ x,
    const float* __restrict__ Wq, const float* __restrict__ bq,
    const float* __restrict__ Wk, const float* __restrict__ bk,
    const float* __restrict__ Wv, const float* __restrict__ bv,
    float* __restrict__ Qw, float* __restrict__ Kw, float* __restrict__ gb)
{
    __shared__ float xt[32][H];        // 64 KiB
    __shared__ float gpart[4][16];
    const int t = threadIdx.x;
    const int row0 = blockIdx.x * 32;

    // load x tile: 32*512 floats = 4096 float4
    {
        const float4* xg = (const float4*)(x + (size_t)row0 * H);
        float4* xl = (float4*)&xt[0][0];
        #pragma unroll
        for (int it = 0; it < 16; ++it) xl[it * 256 + t] = xg[it * 256 + t];
    }
    __syncthreads();

    const int a  = t & 127;
    const int rh = t >> 7;             // 0: rows 0-15, 1: rows 16-31
    float accq[16], acck[16];
    #pragma unroll
    for (int r = 0; r < 16; ++r) { accq[r] = 0.f; acck[r] = 0.f; }

    for (int h4 = 0; h4 < H / 4; ++h4) {
        const int h = h4 * 4;
        const float wq0 = Wq[(h+0)*A + a], wq1 = Wq[(h+1)*A + a];
        const float wq2 = Wq[(h+2)*A + a], wq3 = Wq[(h+3)*A + a];
        const float wk0 = Wk[(h+0)*A + a], wk1 = Wk[(h+1)*A + a];
        const float wk2 = Wk[(h+2)*A + a], wk3 = Wk[(h+3)*A + a];
        #pragma unroll
        for (int r = 0; r < 16; ++r) {
            const float4 xv = *(const float4*)&xt[rh*16 + r][h];
            accq[r] = fmaf(xv.x, wq0, accq[r]);
            accq[r] = fmaf(xv.y, wq1, accq[r]);
            accq[r] = fmaf(xv.z, wq2, accq[r]);
            accq[r] = fmaf(xv.w, wq3, accq[r]);
            acck[r] = fmaf(xv.x, wk0, acck[r]);
            acck[r] = fmaf(xv.y, wk1, acck[r]);
            acck[r] = fmaf(xv.z, wk2, acck[r]);
            acck[r] = fmaf(xv.w, wk3, acck[r]);
        }
    }

    const float bqa = bq[a], bka = bk[a];
    #pragma unroll
    for (int r = 0; r < 16; ++r) {
        accq[r] += bqa; acck[r] += bka;
        const int row = row0 + rh*16 + r;
        Qw[(size_t)row * A + a] = accq[r];
        Kw[(size_t)row * A + a] = acck[r];
    }

    // gate: z = dot(Qw_row, Wv) + bv ; rows 0-15 live in waves 0,1; 16-31 in 2,3
    const float wv = Wv[a];
    const int wid = t >> 6;
    #pragma unroll
    for (int r = 0; r < 16; ++r) {
        float p = accq[r] * wv;
        #pragma unroll
        for (int m = 32; m >= 1; m >>= 1) p += __shfl_xor(p, m, 64);
        if ((t & 63) == 0) gpart[wid][r] = p;
    }
    __syncthreads();
    if (t < 32) {
        const int r = t & 15;
        const int half = t >> 4;           // 0: rows 0-15, 1: rows 16-31
        const float z = gpart[half*2][r] + gpart[half*2 + 1][r] + bv[0];
        gb[row0 + half*16 + r] = 1.f / (1.f + __expf(-z));
    }
}

// ---------------- K2a: scores -> exp -> row-sum ----------------
// One WG per (b, 32-row i-block); loops over all j in tiles of 128.
// Writes unnormalized exp(s) (0 on diagonal) to out, row sums l to ws.
__global__ __launch_bounds__(256) void k2a_scores(
    const float* __restrict__ Qw, const float* __restrict__ Kw,
    float* __restrict__ eout, float* __restrict__ lbuf)
{
    __shared__ float  qt[32][A];       // 16 KiB
    __shared__ float4 kt[128][32];     // 64 KiB, XOR-swizzled float4 chunks
    const int t  = threadIdx.x;
    const int b  = blockIdx.x >> 6;    // N/32 = 64 i-blocks per batch
    const int i0 = (blockIdx.x & 63) * 32;

    // load Q tile (reads are broadcast later; no swizzle needed)
    {
        const float4* qg = (const float4*)(Qw + ((size_t)b * N + i0) * A);
        float4* ql = (float4*)&qt[0][0];
        #pragma unroll
        for (int it = 0; it < 4; ++it) ql[it*256 + t] = qg[it*256 + t];
    }

    const int ty = t >> 5, tx = t & 31;   // rows 4*ty.., cols 4*tx..
    float lsum[4] = {0.f, 0.f, 0.f, 0.f};

    for (int jt = 0; jt < N / 128; ++jt) {
        const int j0 = jt * 128;
        __syncthreads();   // protects qt (jt==0) and kt from previous readers
        {
            const float4* kg4 = (const float4*)(Kw + ((size_t)b * N + j0) * A);
            const int kg = t & 31;
            const int rr = t >> 5;
            #pragma unroll
            for (int it = 0; it < 16; ++it) {
                const int row = it*8 + rr;
                kt[row][kg ^ (row >> 2)] = kg4[row*32 + kg];
            }
        }
        __syncthreads();

        float s[4][4];
        #pragma unroll
        for (int r = 0; r < 4; ++r)
            #pragma unroll
            for (int c = 0; c < 4; ++c) s[r][c] = 0.f;

        #pragma unroll 4
        for (int kg = 0; kg < 32; ++kg) {
            float4 qv[4], kv[4];
            #pragma unroll
            for (int r = 0; r < 4; ++r) qv[r] = *(const float4*)&qt[ty*4 + r][kg*4];
            #pragma unroll
            for (int c = 0; c < 4; ++c) kv[c] = kt[tx*4 + c][kg ^ tx];
            #pragma unroll
            for (int r = 0; r < 4; ++r)
                #pragma unroll
                for (int c = 0; c < 4; ++c) {
                    s[r][c] = fmaf(qv[r].x, kv[c].x, s[r][c]);
                    s[r][c] = fmaf(qv[r].y, kv[c].y, s[r][c]);
                    s[r][c] = fmaf(qv[r].z, kv[c].z, s[r][c]);
                    s[r][c] = fmaf(qv[r].w, kv[c].w, s[r][c]);
                }
        }

        const int jb = j0 + tx*4;
        #pragma unroll
        for (int r = 0; r < 4; ++r) {
            const int i = i0 + ty*4 + r;
            float4 e;
            e.x = (jb + 0 == i) ? 0.f : __expf(s[r][0]);
            e.y = (jb + 1 == i) ? 0.f : __expf(s[r][1]);
            e.z = (jb + 2 == i) ? 0.f : __expf(s[r][2]);
            e.w = (jb + 3 == i) ? 0.f : __expf(s[r][3]);
            lsum[r] += (e.x + e.y) + (e.z + e.w);
            *(float4*)&eout[((size_t)b * N + i) * N + jb] = e;
        }
    }

    // reduce lsum across the 32 tx lanes of each half-wave
    #pragma unroll
    for (int r = 0; r < 4; ++r) {
        float v = lsum[r];
        #pragma unroll
        for (int m = 16; m >= 1; m >>= 1) v += __shfl_xor(v, m, 64);
        if (tx == 0) lbuf[(size_t)b * N + i0 + ty*4 + r] = v;
    }
}

// ---------------- K2b: normalize + gate + diagonal ----------------
__global__ __launch_bounds__(256) void k2b_final(
    float* __restrict__ out, const float* __restrict__ gb,
    const float* __restrict__ lbuf)
{
    const size_t total4 = (size_t)B * N * N / 4;
    const size_t stride = (size_t)gridDim.x * blockDim.x;
    float4* o4 = (float4*)out;
    for (size_t f = (size_t)blockIdx.x * blockDim.x + threadIdx.x; f < total4; f += stride) {
        const int rowf = (int)(f >> 9);           // f / (N/4)
        const int i    = rowf & (N - 1);
        const int j0   = ((int)f & 511) * 4;
        const float g  = gb[rowf];
        const float sc = (1.f - g) / lbuf[rowf];
        float4 e = o4[f];
        float4 o;
        o.x = (j0 + 0 == i) ? g : e.x * sc;
        o.y = (j0 + 1 == i) ? g : e.y * sc;
        o.z = (j0 + 2 == i) ? g : e.z * sc;
        o.w = (j0 + 3 == i) ? g : e.w * sc;
        o4[f] = o;
    }
}

extern "C" void kernel_launch(void* const* d_in, const int* in_sizes, int n_in,
                              void* d_out, int out_size, void* d_ws, size_t ws_size,
                              hipStream_t stream) {
    const float* x  = (const float*)d_in[0];
    const float* Wq = (const float*)d_in[1];
    const float* bq = (const float*)d_in[2];
    const float* Wk = (const float*)d_in[3];
    const float* bk = (const float*)d_in[4];
    const float* Wv = (const float*)d_in[5];
    const float* bv = (const float*)d_in[6];
    float* out = (float*)d_out;

    float* Qw = (float*)d_ws;                    // [B*N, A]  8 MB
    float* Kw = Qw + (size_t)B * N * A;          // [B*N, A]  8 MB
    float* gb = Kw + (size_t)B * N * A;          // [B*N]     64 KB
    float* lb = gb + (size_t)B * N;              // [B*N]     64 KB

    k1_proj<<<(B * N) / 32, 256, 0, stream>>>(x, Wq, bq, Wk, bk, Wv, bv, Qw, Kw, gb);
    k2a_scores<<<B * (N / 32), 256, 0, stream>>>(Qw, Kw, out, lb);
    k2b_final<<<2048, 256, 0, stream>>>(out, gb, lb);
}

// Round 2
// 170.921 us; speedup vs baseline: 1.5525x; 1.5525x over previous
//
#include <hip/hip_runtime.h>
#include <hip/hip_bf16.h>
#include <math.h>

constexpr int B = 8, N = 2048, H = 512, A = 128;

typedef __bf16 bf16x8 __attribute__((ext_vector_type(8)));
typedef float f32x4 __attribute__((ext_vector_type(4)));
typedef unsigned short ushort_t;

__device__ __forceinline__ f32x4 mfma16(bf16x8 a, bf16x8 b, f32x4 c) {
    return __builtin_amdgcn_mfma_f32_16x16x32_bf16(a, b, c, 0, 0, 0);
}

// ---------------- K1: projections + gate + bf16 hi/lo split ----------------
__global__ __launch_bounds__(256) void k1_proj(
    const float* __restrict__ x,
    const float* __restrict__ Wq, const float* __restrict__ bq,
    const float* __restrict__ Wk, const float* __restrict__ bk,
    const float* __restrict__ Wv, const float* __restrict__ bv,
    ushort_t* __restrict__ Qhi, ushort_t* __restrict__ Qlo,
    ushort_t* __restrict__ Khi, ushort_t* __restrict__ Klo,
    float* __restrict__ gb)
{
    __shared__ float xt[32][H];        // 64 KiB
    __shared__ float gpart[4][16];
    const int t = threadIdx.x;
    const int row0 = blockIdx.x * 32;

    {
        const float4* xg = (const float4*)(x + (size_t)row0 * H);
        float4* xl = (float4*)&xt[0][0];
        #pragma unroll
        for (int it = 0; it < 16; ++it) xl[it * 256 + t] = xg[it * 256 + t];
    }
    __syncthreads();

    const int a  = t & 127;
    const int rh = t >> 7;
    float accq[16], acck[16];
    #pragma unroll
    for (int r = 0; r < 16; ++r) { accq[r] = 0.f; acck[r] = 0.f; }

    for (int h4 = 0; h4 < H / 4; ++h4) {
        const int h = h4 * 4;
        const float wq0 = Wq[(h+0)*A + a], wq1 = Wq[(h+1)*A + a];
        const float wq2 = Wq[(h+2)*A + a], wq3 = Wq[(h+3)*A + a];
        const float wk0 = Wk[(h+0)*A + a], wk1 = Wk[(h+1)*A + a];
        const float wk2 = Wk[(h+2)*A + a], wk3 = Wk[(h+3)*A + a];
        #pragma unroll
        for (int r = 0; r < 16; ++r) {
            const float4 xv = *(const float4*)&xt[rh*16 + r][h];
            accq[r] = fmaf(xv.x, wq0, accq[r]);
            accq[r] = fmaf(xv.y, wq1, accq[r]);
            accq[r] = fmaf(xv.z, wq2, accq[r]);
            accq[r] = fmaf(xv.w, wq3, accq[r]);
            acck[r] = fmaf(xv.x, wk0, acck[r]);
            acck[r] = fmaf(xv.y, wk1, acck[r]);
            acck[r] = fmaf(xv.z, wk2, acck[r]);
            acck[r] = fmaf(xv.w, wk3, acck[r]);
        }
    }

    const float bqa = bq[a], bka = bk[a];
    #pragma unroll
    for (int r = 0; r < 16; ++r) {
        accq[r] += bqa; acck[r] += bka;
        const size_t rowa = (size_t)(row0 + rh*16 + r) * A + a;
        __hip_bfloat16 qh_ = __float2bfloat16(accq[r]);
        __hip_bfloat16 ql_ = __float2bfloat16(accq[r] - __bfloat162float(qh_));
        __hip_bfloat16 kh_ = __float2bfloat16(acck[r]);
        __hip_bfloat16 kl_ = __float2bfloat16(acck[r] - __bfloat162float(kh_));
        Qhi[rowa] = __builtin_bit_cast(ushort_t, qh_);
        Qlo[rowa] = __builtin_bit_cast(ushort_t, ql_);
        Khi[rowa] = __builtin_bit_cast(ushort_t, kh_);
        Klo[rowa] = __builtin_bit_cast(ushort_t, kl_);
    }

    // gate
    const float wv = Wv[a];
    const int wid = t >> 6;
    #pragma unroll
    for (int r = 0; r < 16; ++r) {
        float p = accq[r] * wv;
        #pragma unroll
        for (int m = 32; m >= 1; m >>= 1) p += __shfl_xor(p, m, 64);
        if ((t & 63) == 0) gpart[wid][r] = p;
    }
    __syncthreads();
    if (t < 32) {
        const int r = t & 15;
        const int half = t >> 4;
        const float z = gpart[half*2][r] + gpart[half*2 + 1][r] + bv[0];
        gb[row0 + half*16 + r] = 1.f / (1.f + __expf(-z));
    }
}

// ---------------- K2a: MFMA scores -> exp -> partial row sums ----------------
// Grid: 512 WGs = (B * N/128 row-blocks) x 4 j-chunks. 256 threads (4 waves),
// wave (wr,wc) owns a 64x64 quadrant of the 128x128 output tile per j-iter.
__global__ __launch_bounds__(256) void k2a_mfma(
    const ushort_t* __restrict__ Qhi, const ushort_t* __restrict__ Qlo,
    const ushort_t* __restrict__ Khi, const ushort_t* __restrict__ Klo,
    float* __restrict__ eout, float* __restrict__ lpart)
{
    __shared__ ushort_t qh[128*128], ql[128*128], kh[128*128], kl[128*128]; // 128 KiB
    const int t = threadIdx.x;
    const int lane = t & 63, wid = t >> 6;
    const int wr = wid >> 1, wc = wid & 1;
    const int l15 = lane & 15, l4 = lane >> 4;

    const int jc = blockIdx.x & 3;
    const int rb = blockIdx.x >> 2;
    const int b  = rb >> 4;
    const int i0 = (rb & 15) * 128;

    // stage Q tile (hi, lo) with XOR swizzle: byte ^= (row&7)<<4
    {
        const int4* sh = (const int4*)(Qhi + ((size_t)b * N + i0) * A);
        const int4* sl = (const int4*)(Qlo + ((size_t)b * N + i0) * A);
        #pragma unroll
        for (int it = 0; it < 8; ++it) {
            const int idx = it * 256 + t;
            const int row = idx >> 4, c = idx & 15;
            const int dst = (row << 8) + ((c << 4) ^ ((row & 7) << 4));
            *(int4*)((char*)qh + dst) = sh[idx];
            *(int4*)((char*)ql + dst) = sl[idx];
        }
    }

    float lsum[16];
    #pragma unroll
    for (int u = 0; u < 16; ++u) lsum[u] = 0.f;

    for (int jt = 0; jt < 4; ++jt) {
        const int j0 = jc * 512 + jt * 128;
        __syncthreads();
        {
            const int4* sh = (const int4*)(Khi + ((size_t)b * N + j0) * A);
            const int4* sl = (const int4*)(Klo + ((size_t)b * N + j0) * A);
            #pragma unroll
            for (int it = 0; it < 8; ++it) {
                const int idx = it * 256 + t;
                const int row = idx >> 4, c = idx & 15;
                const int dst = (row << 8) + ((c << 4) ^ ((row & 7) << 4));
                *(int4*)((char*)kh + dst) = sh[idx];
                *(int4*)((char*)kl + dst) = sl[idx];
            }
        }
        __syncthreads();

        f32x4 acc[4][4];
        #pragma unroll
        for (int r = 0; r < 4; ++r)
            #pragma unroll
            for (int c = 0; c < 4; ++c) acc[r][c] = {0.f, 0.f, 0.f, 0.f};

        #pragma unroll
        for (int ks = 0; ks < 4; ++ks) {
            const int kb = ks * 64 + l4 * 16;
            bf16x8 ah[4], al[4], bh[4], bl[4];
            #pragma unroll
            for (int r = 0; r < 4; ++r) {
                const int row = wr * 64 + r * 16 + l15;
                const int off = (row << 8) + (kb ^ ((row & 7) << 4));
                ah[r] = *(const bf16x8*)((const char*)qh + off);
                al[r] = *(const bf16x8*)((const char*)ql + off);
            }
            #pragma unroll
            for (int c = 0; c < 4; ++c) {
                const int row = wc * 64 + c * 16 + l15;
                const int off = (row << 8) + (kb ^ ((row & 7) << 4));
                bh[c] = *(const bf16x8*)((const char*)kh + off);
                bl[c] = *(const bf16x8*)((const char*)kl + off);
            }
            #pragma unroll
            for (int r = 0; r < 4; ++r)
                #pragma unroll
                for (int c = 0; c < 4; ++c) {
                    acc[r][c] = mfma16(ah[r], bh[c], acc[r][c]);
                    acc[r][c] = mfma16(ah[r], bl[c], acc[r][c]);
                    acc[r][c] = mfma16(al[r], bh[c], acc[r][c]);
                }
        }

        // epilogue: exp, zero diagonal, store, accumulate row sums
        #pragma unroll
        for (int r = 0; r < 4; ++r) {
            const int i = i0 + wr * 64 + r * 16 + l4 * 4;   // + g
            #pragma unroll
            for (int c = 0; c < 4; ++c) {
                const int j = j0 + wc * 64 + c * 16 + l15;
                float* dst = eout + ((size_t)b * N + i) * N + j;
                #pragma unroll
                for (int g = 0; g < 4; ++g) {
                    const float e = (i + g == j) ? 0.f : __expf(acc[r][c][g]);
                    lsum[r * 4 + g] += e;
                    dst[(size_t)g * N] = e;
                }
            }
        }
    }

    // combine row sums across the two wc waves via LDS (reuse kh)
    __syncthreads();
    float* lred = (float*)kh;
    #pragma unroll
    for (int r = 0; r < 4; ++r)
        #pragma unroll
        for (int g = 0; g < 4; ++g) {
            float v = lsum[r * 4 + g];
            v += __shfl_xor(v, 1); v += __shfl_xor(v, 2);
            v += __shfl_xor(v, 4); v += __shfl_xor(v, 8);
            if (l15 == 0) lred[wc * 128 + wr * 64 + r * 16 + l4 * 4 + g] = v;
        }
    __syncthreads();
    if (t < 128)
        lpart[(size_t)jc * (B * N) + (size_t)b * N + i0 + t] = lred[t] + lred[128 + t];
}

// ---------------- K2b: normalize + gate + diagonal (in place) ----------------
__global__ __launch_bounds__(256) void k2b_final(
    float* __restrict__ out, const float* __restrict__ gb,
    const float* __restrict__ lpart)
{
    const size_t total4 = (size_t)B * N * N / 4;
    const size_t stride = (size_t)gridDim.x * blockDim.x;
    const size_t BN = (size_t)B * N;
    float4* o4 = (float4*)out;
    for (size_t f = (size_t)blockIdx.x * blockDim.x + threadIdx.x; f < total4; f += stride) {
        const int rowf = (int)(f >> 9);
        const int i    = rowf & (N - 1);
        const int j0   = ((int)f & 511) * 4;
        const float g  = gb[rowf];
        const float l  = lpart[rowf] + lpart[BN + rowf] + lpart[2*BN + rowf] + lpart[3*BN + rowf];
        const float sc = (1.f - g) / l;
        float4 e = o4[f];
        float4 o;
        o.x = (j0 + 0 == i) ? g : e.x * sc;
        o.y = (j0 + 1 == i) ? g : e.y * sc;
        o.z = (j0 + 2 == i) ? g : e.z * sc;
        o.w = (j0 + 3 == i) ? g : e.w * sc;
        o4[f] = o;
    }
}

extern "C" void kernel_launch(void* const* d_in, const int* in_sizes, int n_in,
                              void* d_out, int out_size, void* d_ws, size_t ws_size,
                              hipStream_t stream) {
    const float* x  = (const float*)d_in[0];
    const float* Wq = (const float*)d_in[1];
    const float* bq = (const float*)d_in[2];
    const float* Wk = (const float*)d_in[3];
    const float* bk = (const float*)d_in[4];
    const float* Wv = (const float*)d_in[5];
    const float* bv = (const float*)d_in[6];
    float* out = (float*)d_out;

    ushort_t* Qhi = (ushort_t*)d_ws;                     // 4 MB each
    ushort_t* Qlo = Qhi + (size_t)B * N * A;
    ushort_t* Khi = Qlo + (size_t)B * N * A;
    ushort_t* Klo = Khi + (size_t)B * N * A;
    float* gb = (float*)(Klo + (size_t)B * N * A);       // 64 KB
    float* lp = gb + (size_t)B * N;                      // 256 KB (4 partials)

    k1_proj<<<(B * N) / 32, 256, 0, stream>>>(x, Wq, bq, Wk, bk, Wv, bv,
                                              Qhi, Qlo, Khi, Klo, gb);
    k2a_mfma<<<B * (N / 128) * 4, 256, 0, stream>>>(Qhi, Qlo, Khi, Klo, out, lp);
    k2b_final<<<2048, 256, 0, stream>>>(out, gb, lp);
}

// Round 3
// 136.731 us; speedup vs baseline: 1.9408x; 1.2501x over previous
//
#include <hip/hip_runtime.h>
#include <hip/hip_bf16.h>
#include <math.h>

constexpr int B = 8, N = 2048, H = 512, A = 128;

typedef __bf16 bf16x8 __attribute__((ext_vector_type(8)));
typedef float f32x4 __attribute__((ext_vector_type(4)));
typedef unsigned short ushort_t;
typedef unsigned int uint_t;

__device__ __forceinline__ f32x4 mfma16(bf16x8 a, bf16x8 b, f32x4 c) {
    return __builtin_amdgcn_mfma_f32_16x16x32_bf16(a, b, c, 0, 0, 0);
}
__device__ __forceinline__ ushort_t f2bf(float v) {
    return __builtin_bit_cast(ushort_t, __float2bfloat16(v));
}
__device__ __forceinline__ float bf2f(ushort_t u) {
    return __bfloat162float(__builtin_bit_cast(__hip_bfloat16, u));
}

// ---------------- K0: transpose + hi/lo split the weights ----------------
__global__ __launch_bounds__(256) void k0_conv(
    const float* __restrict__ Wq, const float* __restrict__ Wk,
    ushort_t* __restrict__ WqTh, ushort_t* __restrict__ WqTl,
    ushort_t* __restrict__ WkTh, ushort_t* __restrict__ WkTl)
{
    const int id = blockIdx.x * 256 + threadIdx.x;   // 65536 = 512*128
    const int k = id >> 7, n = id & 127;
    const float vq = Wq[id];
    const ushort_t qh = f2bf(vq);
    const ushort_t ql = f2bf(vq - bf2f(qh));
    WqTh[n * 512 + k] = qh; WqTl[n * 512 + k] = ql;
    const float vk = Wk[id];
    const ushort_t kh = f2bf(vk);
    const ushort_t kl = f2bf(vk - bf2f(kh));
    WkTh[n * 512 + k] = kh; WkTl[n * 512 + k] = kl;
}

// ---------------- K1: MFMA projections + gate ----------------
// 256 WGs x 64 rows. 4 waves: wave w covers all 64 rows x 64 cols of
// (w<2 ? Q : K), col half = (w&1). x staged per 256-K-chunk as hi/lo bf16.
__global__ __launch_bounds__(256) void k1_mfma(
    const float* __restrict__ x,
    const ushort_t* __restrict__ WqTh, const ushort_t* __restrict__ WqTl,
    const ushort_t* __restrict__ WkTh, const ushort_t* __restrict__ WkTl,
    const float* __restrict__ bq, const float* __restrict__ bk,
    const float* __restrict__ Wv, const float* __restrict__ bv,
    uint_t* __restrict__ QP, uint_t* __restrict__ KP, float* __restrict__ gb)
{
    __shared__ ushort_t xh[64 * 256], xl[64 * 256];   // 64 KiB
    __shared__ float gred[2][64];
    const int t = threadIdx.x;
    const int lane = t & 63, w = t >> 6;
    const int l15 = lane & 15, l4 = lane >> 4;
    const int m0 = blockIdx.x * 64;

    f32x4 acc[4][4];
    #pragma unroll
    for (int r = 0; r < 4; ++r)
        #pragma unroll
        for (int c = 0; c < 4; ++c) acc[r][c] = {0.f, 0.f, 0.f, 0.f};

    const ushort_t* WTh = (w < 2) ? WqTh : WkTh;
    const ushort_t* WTl = (w < 2) ? WqTl : WkTl;
    const int colbase = (w & 1) * 64;

    for (int ck = 0; ck < 2; ++ck) {
        __syncthreads();
        // stage x[64][256] f32 -> hi/lo bf16, XOR-swizzled
        #pragma unroll
        for (int it = 0; it < 16; ++it) {
            const int idx = it * 256 + t;
            const int row = idx >> 6, c4 = idx & 63;
            const float4 v = *(const float4*)(x + (size_t)(m0 + row) * H + ck * 256 + c4 * 4);
            const ushort_t h0 = f2bf(v.x), h1 = f2bf(v.y), h2 = f2bf(v.z), h3 = f2bf(v.w);
            const ushort_t e0 = f2bf(v.x - bf2f(h0)), e1 = f2bf(v.y - bf2f(h1));
            const ushort_t e2 = f2bf(v.z - bf2f(h2)), e3 = f2bf(v.w - bf2f(h3));
            uint2 hh, ll;
            hh.x = (uint_t)h0 | ((uint_t)h1 << 16); hh.y = (uint_t)h2 | ((uint_t)h3 << 16);
            ll.x = (uint_t)e0 | ((uint_t)e1 << 16); ll.y = (uint_t)e2 | ((uint_t)e3 << 16);
            const int base = row * 512 + ((((c4 >> 1) << 4)) ^ ((row & 7) << 4)) + (c4 & 1) * 8;
            *(uint2*)((char*)xh + base) = hh;
            *(uint2*)((char*)xl + base) = ll;
        }
        __syncthreads();

        #pragma unroll
        for (int ks = 0; ks < 8; ++ks) {
            bf16x8 ah[4], al[4], bh[4], bl[4];
            const int kb = ks * 64 + l4 * 16;
            #pragma unroll
            for (int rb = 0; rb < 4; ++rb) {
                const int row = rb * 16 + l15;
                const int off = row * 512 + (kb ^ ((row & 7) << 4));
                ah[rb] = *(const bf16x8*)((const char*)xh + off);
                al[rb] = *(const bf16x8*)((const char*)xl + off);
            }
            const int kg = ck * 256 + ks * 32 + l4 * 8;
            #pragma unroll
            for (int cb = 0; cb < 4; ++cb) {
                const size_t woff = (size_t)(colbase + cb * 16 + l15) * 512 + kg;
                bh[cb] = *(const bf16x8*)(WTh + woff);
                bl[cb] = *(const bf16x8*)(WTl + woff);
            }
            #pragma unroll
            for (int rb = 0; rb < 4; ++rb)
                #pragma unroll
                for (int cb = 0; cb < 4; ++cb) {
                    acc[rb][cb] = mfma16(ah[rb], bh[cb], acc[rb][cb]);
                    acc[rb][cb] = mfma16(ah[rb], bl[cb], acc[rb][cb]);
                    acc[rb][cb] = mfma16(al[rb], bh[cb], acc[rb][cb]);
                }
        }
    }

    // bias add + gate partials
    const float* bias = (w < 2) ? bq : bk;
    float bb[4], wv[4];
    #pragma unroll
    for (int cb = 0; cb < 4; ++cb) {
        bb[cb] = bias[colbase + cb * 16 + l15];
        wv[cb] = Wv[colbase + cb * 16 + l15];
    }
    float p[4][4];
    #pragma unroll
    for (int rb = 0; rb < 4; ++rb)
        #pragma unroll
        for (int g = 0; g < 4; ++g) {
            float ps = 0.f;
            #pragma unroll
            for (int cb = 0; cb < 4; ++cb) {
                const float v = acc[rb][cb][g] + bb[cb];
                acc[rb][cb][g] = v;
                ps = fmaf(v, wv[cb], ps);
            }
            p[rb][g] = ps;
        }

    // packed hi/lo stores
    uint_t* OP = (w < 2) ? QP : KP;
    #pragma unroll
    for (int rb = 0; rb < 4; ++rb) {
        const int row = m0 + rb * 16 + l4 * 4;
        #pragma unroll
        for (int cb = 0; cb < 4; ++cb) {
            const int col = colbase + cb * 16 + l15;
            #pragma unroll
            for (int g = 0; g < 4; ++g) {
                const float v = acc[rb][cb][g];
                const ushort_t hi = f2bf(v);
                const ushort_t lo = f2bf(v - bf2f(hi));
                OP[(size_t)(row + g) * A + col] = (uint_t)hi | ((uint_t)lo << 16);
            }
        }
    }

    // gate: reduce p over the 16 col-lanes, combine the two Q-waves
    if (w < 2) {
        #pragma unroll
        for (int rb = 0; rb < 4; ++rb)
            #pragma unroll
            for (int g = 0; g < 4; ++g) {
                float v = p[rb][g];
                v += __shfl_xor(v, 1); v += __shfl_xor(v, 2);
                v += __shfl_xor(v, 4); v += __shfl_xor(v, 8);
                if (l15 == 0) gred[w][rb * 16 + l4 * 4 + g] = v;
            }
    }
    __syncthreads();
    if (t < 64) {
        const float z = gred[0][t] + gred[1][t] + bv[0];
        gb[m0 + t] = 1.f / (1.f + __expf(-z));
    }
}

// ---------------- K2a: MFMA scores -> exp -> partial row sums ----------------
__global__ __launch_bounds__(256) void k2a_mfma(
    const uint_t* __restrict__ QP, const uint_t* __restrict__ KP,
    float* __restrict__ eout, float* __restrict__ lpart)
{
    __shared__ ushort_t qh[128*128], ql[128*128], kh[128*128], kl[128*128]; // 128 KiB
    const int t = threadIdx.x;
    const int lane = t & 63, wid = t >> 6;
    const int wr = wid >> 1, wc = wid & 1;
    const int l15 = lane & 15, l4 = lane >> 4;

    const int jc = blockIdx.x & 3;
    const int rb_ = blockIdx.x >> 2;
    const int b  = rb_ >> 4;
    const int i0 = (rb_ & 15) * 128;

    // stage Q tile (unpack packed hi/lo), XOR swizzle
    {
        const uint4* sq = (const uint4*)(QP + ((size_t)b * N + i0) * A);
        #pragma unroll
        for (int it = 0; it < 16; ++it) {
            const int idx = it * 256 + t;
            const int row = idx >> 5, c4 = idx & 31;
            const uint4 v = sq[idx];
            uint2 hh, ll;
            hh.x = (v.x & 0xffffu) | ((v.y & 0xffffu) << 16);
            hh.y = (v.z & 0xffffu) | ((v.w & 0xffffu) << 16);
            ll.x = (v.x >> 16) | (v.y & 0xffff0000u);
            ll.y = (v.z >> 16) | (v.w & 0xffff0000u);
            const int base = (row << 8) + (((c4 >> 1) << 4) ^ ((row & 7) << 4)) + (c4 & 1) * 8;
            *(uint2*)((char*)qh + base) = hh;
            *(uint2*)((char*)ql + base) = ll;
        }
    }

    float lsum[16];
    #pragma unroll
    for (int u = 0; u < 16; ++u) lsum[u] = 0.f;

    for (int jt = 0; jt < 4; ++jt) {
        const int j0 = jc * 512 + jt * 128;
        __syncthreads();
        {
            const uint4* sk = (const uint4*)(KP + ((size_t)b * N + j0) * A);
            #pragma unroll
            for (int it = 0; it < 16; ++it) {
                const int idx = it * 256 + t;
                const int row = idx >> 5, c4 = idx & 31;
                const uint4 v = sk[idx];
                uint2 hh, ll;
                hh.x = (v.x & 0xffffu) | ((v.y & 0xffffu) << 16);
                hh.y = (v.z & 0xffffu) | ((v.w & 0xffffu) << 16);
                ll.x = (v.x >> 16) | (v.y & 0xffff0000u);
                ll.y = (v.z >> 16) | (v.w & 0xffff0000u);
                const int base = (row << 8) + (((c4 >> 1) << 4) ^ ((row & 7) << 4)) + (c4 & 1) * 8;
                *(uint2*)((char*)kh + base) = hh;
                *(uint2*)((char*)kl + base) = ll;
            }
        }
        __syncthreads();

        f32x4 acc[4][4];
        #pragma unroll
        for (int r = 0; r < 4; ++r)
            #pragma unroll
            for (int c = 0; c < 4; ++c) acc[r][c] = {0.f, 0.f, 0.f, 0.f};

        #pragma unroll
        for (int ks = 0; ks < 4; ++ks) {
            const int kb = ks * 64 + l4 * 16;
            bf16x8 ah[4], al[4], bh[4], bl[4];
            #pragma unroll
            for (int r = 0; r < 4; ++r) {
                const int row = wr * 64 + r * 16 + l15;
                const int off = (row << 8) + (kb ^ ((row & 7) << 4));
                ah[r] = *(const bf16x8*)((const char*)qh + off);
                al[r] = *(const bf16x8*)((const char*)ql + off);
            }
            #pragma unroll
            for (int c = 0; c < 4; ++c) {
                const int row = wc * 64 + c * 16 + l15;
                const int off = (row << 8) + (kb ^ ((row & 7) << 4));
                bh[c] = *(const bf16x8*)((const char*)kh + off);
                bl[c] = *(const bf16x8*)((const char*)kl + off);
            }
            #pragma unroll
            for (int r = 0; r < 4; ++r)
                #pragma unroll
                for (int c = 0; c < 4; ++c) {
                    acc[r][c] = mfma16(ah[r], bh[c], acc[r][c]);
                    acc[r][c] = mfma16(ah[r], bl[c], acc[r][c]);
                    acc[r][c] = mfma16(al[r], bh[c], acc[r][c]);
                }
        }

        #pragma unroll
        for (int r = 0; r < 4; ++r) {
            const int i = i0 + wr * 64 + r * 16 + l4 * 4;
            #pragma unroll
            for (int c = 0; c < 4; ++c) {
                const int j = j0 + wc * 64 + c * 16 + l15;
                float* dst = eout + ((size_t)b * N + i) * N + j;
                #pragma unroll
                for (int g = 0; g < 4; ++g) {
                    const float e = (i + g == j) ? 0.f : __expf(acc[r][c][g]);
                    lsum[r * 4 + g] += e;
                    dst[(size_t)g * N] = e;
                }
            }
        }
    }

    __syncthreads();
    float* lred = (float*)kh;
    #pragma unroll
    for (int r = 0; r < 4; ++r)
        #pragma unroll
        for (int g = 0; g < 4; ++g) {
            float v = lsum[r * 4 + g];
            v += __shfl_xor(v, 1); v += __shfl_xor(v, 2);
            v += __shfl_xor(v, 4); v += __shfl_xor(v, 8);
            if (l15 == 0) lred[wc * 128 + wr * 64 + r * 16 + l4 * 4 + g] = v;
        }
    __syncthreads();
    if (t < 128)
        lpart[(size_t)jc * (B * N) + (size_t)b * N + i0 + t] = lred[t] + lred[128 + t];
}

// ---------------- K2b: normalize + gate + diagonal (in place) ----------------
__global__ __launch_bounds__(256) void k2b_final(
    float* __restrict__ out, const float* __restrict__ gb,
    const float* __restrict__ lpart)
{
    const size_t total4 = (size_t)B * N * N / 4;
    const size_t stride = (size_t)gridDim.x * blockDim.x;
    const size_t BN = (size_t)B * N;
    float4* o4 = (float4*)out;
    for (size_t f = (size_t)blockIdx.x * blockDim.x + threadIdx.x; f < total4; f += stride) {
        const int rowf = (int)(f >> 9);
        const int i    = rowf & (N - 1);
        const int j0   = ((int)f & 511) * 4;
        const float g  = gb[rowf];
        const float l  = lpart[rowf] + lpart[BN + rowf] + lpart[2*BN + rowf] + lpart[3*BN + rowf];
        const float sc = (1.f - g) / l;
        float4 e = o4[f];
        float4 o;
        o.x = (j0 + 0 == i) ? g : e.x * sc;
        o.y = (j0 + 1 == i) ? g : e.y * sc;
        o.z = (j0 + 2 == i) ? g : e.z * sc;
        o.w = (j0 + 3 == i) ? g : e.w * sc;
        o4[f] = o;
    }
}

extern "C" void kernel_launch(void* const* d_in, const int* in_sizes, int n_in,
                              void* d_out, int out_size, void* d_ws, size_t ws_size,
                              hipStream_t stream) {
    const float* x  = (const float*)d_in[0];
    const float* Wq = (const float*)d_in[1];
    const float* bq = (const float*)d_in[2];
    const float* Wk = (const float*)d_in[3];
    const float* bk = (const float*)d_in[4];
    const float* Wv = (const float*)d_in[5];
    const float* bv = (const float*)d_in[6];
    float* out = (float*)d_out;

    uint_t* QP = (uint_t*)d_ws;                          // 8 MB
    uint_t* KP = QP + (size_t)B * N * A;                 // 8 MB
    ushort_t* WqTh = (ushort_t*)(KP + (size_t)B * N * A);
    ushort_t* WqTl = WqTh + H * A;
    ushort_t* WkTh = WqTl + H * A;
    ushort_t* WkTl = WkTh + H * A;
    float* gb = (float*)(WkTl + H * A);                  // 64 KB
    float* lp = gb + (size_t)B * N;                      // 256 KB

    k0_conv<<<(H * A) / 256, 256, 0, stream>>>(Wq, Wk, WqTh, WqTl, WkTh, WkTl);
    k1_mfma<<<(B * N) / 64, 256, 0, stream>>>(x, WqTh, WqTl, WkTh, WkTl,
                                              bq, bk, Wv, bv, QP, KP, gb);
    k2a_mfma<<<B * (N / 128) * 4, 256, 0, stream>>>(QP, KP, out, lp);
    k2b_final<<<2048, 256, 0, stream>>>(out, gb, lp);
}

// Round 4
// 124.680 us; speedup vs baseline: 2.1283x; 1.0967x over previous
//
#include <hip/hip_runtime.h>
#include <hip/hip_bf16.h>
#include <math.h>

constexpr int B = 8, N = 2048, H = 512, A = 128;

typedef __bf16 bf16x8 __attribute__((ext_vector_type(8)));
typedef float f32x4 __attribute__((ext_vector_type(4)));
typedef unsigned short ushort_t;
typedef unsigned int uint_t;

__device__ __forceinline__ f32x4 mfma16(bf16x8 a, bf16x8 b, f32x4 c) {
    return __builtin_amdgcn_mfma_f32_16x16x32_bf16(a, b, c, 0, 0, 0);
}
__device__ __forceinline__ ushort_t f2bf(float v) {
    return __builtin_bit_cast(ushort_t, __float2bfloat16(v));
}
__device__ __forceinline__ float bf2f(ushort_t u) {
    return __bfloat162float(__builtin_bit_cast(__hip_bfloat16, u));
}

// ---------------- K0: transpose + hi/lo split the weights ----------------
__global__ __launch_bounds__(256) void k0_conv(
    const float* __restrict__ Wq, const float* __restrict__ Wk,
    ushort_t* __restrict__ WqTh, ushort_t* __restrict__ WqTl,
    ushort_t* __restrict__ WkTh, ushort_t* __restrict__ WkTl)
{
    const int id = blockIdx.x * 256 + threadIdx.x;   // 65536 = 512*128
    const int k = id >> 7, n = id & 127;
    const float vq = Wq[id];
    const ushort_t qh = f2bf(vq);
    const ushort_t ql = f2bf(vq - bf2f(qh));
    WqTh[n * 512 + k] = qh; WqTl[n * 512 + k] = ql;
    const float vk = Wk[id];
    const ushort_t kh = f2bf(vk);
    const ushort_t kl = f2bf(vk - bf2f(kh));
    WkTh[n * 512 + k] = kh; WkTl[n * 512 + k] = kl;
}

// ---------------- K1: MFMA projections + gate ----------------
__global__ __launch_bounds__(256) void k1_mfma(
    const float* __restrict__ x,
    const ushort_t* __restrict__ WqTh, const ushort_t* __restrict__ WqTl,
    const ushort_t* __restrict__ WkTh, const ushort_t* __restrict__ WkTl,
    const float* __restrict__ bq, const float* __restrict__ bk,
    const float* __restrict__ Wv, const float* __restrict__ bv,
    uint_t* __restrict__ QP, uint_t* __restrict__ KP, float* __restrict__ gb)
{
    __shared__ ushort_t xh[64 * 256], xl[64 * 256];   // 64 KiB
    __shared__ float gred[2][64];
    const int t = threadIdx.x;
    const int lane = t & 63, w = t >> 6;
    const int l15 = lane & 15, l4 = lane >> 4;
    const int m0 = blockIdx.x * 64;

    f32x4 acc[4][4];
    #pragma unroll
    for (int r = 0; r < 4; ++r)
        #pragma unroll
        for (int c = 0; c < 4; ++c) acc[r][c] = {0.f, 0.f, 0.f, 0.f};

    const ushort_t* WTh = (w < 2) ? WqTh : WkTh;
    const ushort_t* WTl = (w < 2) ? WqTl : WkTl;
    const int colbase = (w & 1) * 64;

    for (int ck = 0; ck < 2; ++ck) {
        __syncthreads();
        #pragma unroll
        for (int it = 0; it < 16; ++it) {
            const int idx = it * 256 + t;
            const int row = idx >> 6, c4 = idx & 63;
            const float4 v = *(const float4*)(x + (size_t)(m0 + row) * H + ck * 256 + c4 * 4);
            const ushort_t h0 = f2bf(v.x), h1 = f2bf(v.y), h2 = f2bf(v.z), h3 = f2bf(v.w);
            const ushort_t e0 = f2bf(v.x - bf2f(h0)), e1 = f2bf(v.y - bf2f(h1));
            const ushort_t e2 = f2bf(v.z - bf2f(h2)), e3 = f2bf(v.w - bf2f(h3));
            uint2 hh, ll;
            hh.x = (uint_t)h0 | ((uint_t)h1 << 16); hh.y = (uint_t)h2 | ((uint_t)h3 << 16);
            ll.x = (uint_t)e0 | ((uint_t)e1 << 16); ll.y = (uint_t)e2 | ((uint_t)e3 << 16);
            const int base = row * 512 + ((((c4 >> 1) << 4)) ^ ((row & 7) << 4)) + (c4 & 1) * 8;
            *(uint2*)((char*)xh + base) = hh;
            *(uint2*)((char*)xl + base) = ll;
        }
        __syncthreads();

        #pragma unroll
        for (int ks = 0; ks < 8; ++ks) {
            bf16x8 ah[4], al[4], bh[4], bl[4];
            const int kb = ks * 64 + l4 * 16;
            #pragma unroll
            for (int rb = 0; rb < 4; ++rb) {
                const int row = rb * 16 + l15;
                const int off = row * 512 + (kb ^ ((row & 7) << 4));
                ah[rb] = *(const bf16x8*)((const char*)xh + off);
                al[rb] = *(const bf16x8*)((const char*)xl + off);
            }
            const int kg = ck * 256 + ks * 32 + l4 * 8;
            #pragma unroll
            for (int cb = 0; cb < 4; ++cb) {
                const size_t woff = (size_t)(colbase + cb * 16 + l15) * 512 + kg;
                bh[cb] = *(const bf16x8*)(WTh + woff);
                bl[cb] = *(const bf16x8*)(WTl + woff);
            }
            #pragma unroll
            for (int rb = 0; rb < 4; ++rb)
                #pragma unroll
                for (int cb = 0; cb < 4; ++cb) {
                    acc[rb][cb] = mfma16(ah[rb], bh[cb], acc[rb][cb]);
                    acc[rb][cb] = mfma16(ah[rb], bl[cb], acc[rb][cb]);
                    acc[rb][cb] = mfma16(al[rb], bh[cb], acc[rb][cb]);
                }
        }
    }

    const float* bias = (w < 2) ? bq : bk;
    float bb[4], wv[4];
    #pragma unroll
    for (int cb = 0; cb < 4; ++cb) {
        bb[cb] = bias[colbase + cb * 16 + l15];
        wv[cb] = Wv[colbase + cb * 16 + l15];
    }
    float p[4][4];
    #pragma unroll
    for (int rb = 0; rb < 4; ++rb)
        #pragma unroll
        for (int g = 0; g < 4; ++g) {
            float ps = 0.f;
            #pragma unroll
            for (int cb = 0; cb < 4; ++cb) {
                const float v = acc[rb][cb][g] + bb[cb];
                acc[rb][cb][g] = v;
                ps = fmaf(v, wv[cb], ps);
            }
            p[rb][g] = ps;
        }

    uint_t* OP = (w < 2) ? QP : KP;
    #pragma unroll
    for (int rb = 0; rb < 4; ++rb) {
        const int row = m0 + rb * 16 + l4 * 4;
        #pragma unroll
        for (int cb = 0; cb < 4; ++cb) {
            const int col = colbase + cb * 16 + l15;
            #pragma unroll
            for (int g = 0; g < 4; ++g) {
                const float v = acc[rb][cb][g];
                const ushort_t hi = f2bf(v);
                const ushort_t lo = f2bf(v - bf2f(hi));
                OP[(size_t)(row + g) * A + col] = (uint_t)hi | ((uint_t)lo << 16);
            }
        }
    }

    if (w < 2) {
        #pragma unroll
        for (int rb = 0; rb < 4; ++rb)
            #pragma unroll
            for (int g = 0; g < 4; ++g) {
                float v = p[rb][g];
                v += __shfl_xor(v, 1); v += __shfl_xor(v, 2);
                v += __shfl_xor(v, 4); v += __shfl_xor(v, 8);
                if (l15 == 0) gred[w][rb * 16 + l4 * 4 + g] = v;
            }
    }
    __syncthreads();
    if (t < 64) {
        const float z = gred[0][t] + gred[1][t] + bv[0];
        gb[m0 + t] = 1.f / (1.f + __expf(-z));
    }
}

// ---------------- K2a: MFMA scores -> exp(bf16) -> partial row sums ----------------
__global__ __launch_bounds__(256) void k2a_mfma(
    const uint_t* __restrict__ QP, const uint_t* __restrict__ KP,
    ushort_t* __restrict__ eout, float* __restrict__ lpart)
{
    __shared__ ushort_t qh[128*128], ql[128*128], kh[128*128], kl[128*128]; // 128 KiB
    const int t = threadIdx.x;
    const int lane = t & 63, wid = t >> 6;
    const int wr = wid >> 1, wc = wid & 1;
    const int l15 = lane & 15, l4 = lane >> 4;

    const int jc = blockIdx.x & 3;
    const int rb_ = blockIdx.x >> 2;
    const int b  = rb_ >> 4;
    const int i0 = (rb_ & 15) * 128;

    {
        const uint4* sq = (const uint4*)(QP + ((size_t)b * N + i0) * A);
        #pragma unroll
        for (int it = 0; it < 16; ++it) {
            const int idx = it * 256 + t;
            const int row = idx >> 5, c4 = idx & 31;
            const uint4 v = sq[idx];
            uint2 hh, ll;
            hh.x = (v.x & 0xffffu) | ((v.y & 0xffffu) << 16);
            hh.y = (v.z & 0xffffu) | ((v.w & 0xffffu) << 16);
            ll.x = (v.x >> 16) | (v.y & 0xffff0000u);
            ll.y = (v.z >> 16) | (v.w & 0xffff0000u);
            const int base = (row << 8) + (((c4 >> 1) << 4) ^ ((row & 7) << 4)) + (c4 & 1) * 8;
            *(uint2*)((char*)qh + base) = hh;
            *(uint2*)((char*)ql + base) = ll;
        }
    }

    float lsum[16];
    #pragma unroll
    for (int u = 0; u < 16; ++u) lsum[u] = 0.f;

    for (int jt = 0; jt < 4; ++jt) {
        const int j0 = jc * 512 + jt * 128;
        __syncthreads();
        {
            const uint4* sk = (const uint4*)(KP + ((size_t)b * N + j0) * A);
            #pragma unroll
            for (int it = 0; it < 16; ++it) {
                const int idx = it * 256 + t;
                const int row = idx >> 5, c4 = idx & 31;
                const uint4 v = sk[idx];
                uint2 hh, ll;
                hh.x = (v.x & 0xffffu) | ((v.y & 0xffffu) << 16);
                hh.y = (v.z & 0xffffu) | ((v.w & 0xffffu) << 16);
                ll.x = (v.x >> 16) | (v.y & 0xffff0000u);
                ll.y = (v.z >> 16) | (v.w & 0xffff0000u);
                const int base = (row << 8) + (((c4 >> 1) << 4) ^ ((row & 7) << 4)) + (c4 & 1) * 8;
                *(uint2*)((char*)kh + base) = hh;
                *(uint2*)((char*)kl + base) = ll;
            }
        }
        __syncthreads();

        f32x4 acc[4][4];
        #pragma unroll
        for (int r = 0; r < 4; ++r)
            #pragma unroll
            for (int c = 0; c < 4; ++c) acc[r][c] = {0.f, 0.f, 0.f, 0.f};

        #pragma unroll
        for (int ks = 0; ks < 4; ++ks) {
            const int kb = ks * 64 + l4 * 16;
            bf16x8 ah[4], al[4], bh[4], bl[4];
            #pragma unroll
            for (int r = 0; r < 4; ++r) {
                const int row = wr * 64 + r * 16 + l15;
                const int off = (row << 8) + (kb ^ ((row & 7) << 4));
                ah[r] = *(const bf16x8*)((const char*)qh + off);
                al[r] = *(const bf16x8*)((const char*)ql + off);
            }
            #pragma unroll
            for (int c = 0; c < 4; ++c) {
                const int row = wc * 64 + c * 16 + l15;
                const int off = (row << 8) + (kb ^ ((row & 7) << 4));
                bh[c] = *(const bf16x8*)((const char*)kh + off);
                bl[c] = *(const bf16x8*)((const char*)kl + off);
            }
            #pragma unroll
            for (int r = 0; r < 4; ++r)
                #pragma unroll
                for (int c = 0; c < 4; ++c) {
                    acc[r][c] = mfma16(ah[r], bh[c], acc[r][c]);
                    acc[r][c] = mfma16(ah[r], bl[c], acc[r][c]);
                    acc[r][c] = mfma16(al[r], bh[c], acc[r][c]);
                }
        }

        #pragma unroll
        for (int r = 0; r < 4; ++r) {
            const int i = i0 + wr * 64 + r * 16 + l4 * 4;
            #pragma unroll
            for (int c = 0; c < 4; ++c) {
                const int j = j0 + wc * 64 + c * 16 + l15;
                ushort_t* dst = eout + ((size_t)b * N + i) * N + j;
                #pragma unroll
                for (int g = 0; g < 4; ++g) {
                    const float e = (i + g == j) ? 0.f : __expf(acc[r][c][g]);
                    lsum[r * 4 + g] += e;
                    dst[(size_t)g * N] = f2bf(e);
                }
            }
        }
    }

    __syncthreads();
    float* lred = (float*)kh;
    #pragma unroll
    for (int r = 0; r < 4; ++r)
        #pragma unroll
        for (int g = 0; g < 4; ++g) {
            float v = lsum[r * 4 + g];
            v += __shfl_xor(v, 1); v += __shfl_xor(v, 2);
            v += __shfl_xor(v, 4); v += __shfl_xor(v, 8);
            if (l15 == 0) lred[wc * 128 + wr * 64 + r * 16 + l4 * 4 + g] = v;
        }
    __syncthreads();
    if (t < 128)
        lpart[(size_t)jc * (B * N) + (size_t)b * N + i0 + t] = lred[t] + lred[128 + t];
}

// ---------------- K2b: bf16 e -> normalized f32 out + gate + diagonal ----------------
__global__ __launch_bounds__(256) void k2b_final(
    const ushort_t* __restrict__ ebuf, float* __restrict__ out,
    const float* __restrict__ gb, const float* __restrict__ lpart)
{
    const size_t total8 = (size_t)B * N * N / 8;
    const size_t stride = (size_t)gridDim.x * blockDim.x;
    const size_t BN = (size_t)B * N;
    for (size_t f = (size_t)blockIdx.x * blockDim.x + threadIdx.x; f < total8; f += stride) {
        const int rowf = (int)(f >> 8);            // f / (N/8)
        const int i    = rowf & (N - 1);
        const int j0   = ((int)f & 255) * 8;
        const float g  = gb[rowf];
        const float l  = lpart[rowf] + lpart[BN + rowf] + lpart[2*BN + rowf] + lpart[3*BN + rowf];
        const float sc = (1.f - g) / l;
        const uint4 ev = *(const uint4*)(ebuf + f * 8);
        float4 o0, o1;
        o0.x = (j0 + 0 == i) ? g : bf2f((ushort_t)(ev.x & 0xffffu)) * sc;
        o0.y = (j0 + 1 == i) ? g : bf2f((ushort_t)(ev.x >> 16)) * sc;
        o0.z = (j0 + 2 == i) ? g : bf2f((ushort_t)(ev.y & 0xffffu)) * sc;
        o0.w = (j0 + 3 == i) ? g : bf2f((ushort_t)(ev.y >> 16)) * sc;
        o1.x = (j0 + 4 == i) ? g : bf2f((ushort_t)(ev.z & 0xffffu)) * sc;
        o1.y = (j0 + 5 == i) ? g : bf2f((ushort_t)(ev.z >> 16)) * sc;
        o1.z = (j0 + 6 == i) ? g : bf2f((ushort_t)(ev.w & 0xffffu)) * sc;
        o1.w = (j0 + 7 == i) ? g : bf2f((ushort_t)(ev.w >> 16)) * sc;
        float* dst = out + (size_t)rowf * N + j0;
        *(float4*)dst = o0;
        *(float4*)(dst + 4) = o1;
    }
}

extern "C" void kernel_launch(void* const* d_in, const int* in_sizes, int n_in,
                              void* d_out, int out_size, void* d_ws, size_t ws_size,
                              hipStream_t stream) {
    const float* x  = (const float*)d_in[0];
    const float* Wq = (const float*)d_in[1];
    const float* bq = (const float*)d_in[2];
    const float* Wk = (const float*)d_in[3];
    const float* bk = (const float*)d_in[4];
    const float* Wv = (const float*)d_in[5];
    const float* bv = (const float*)d_in[6];
    float* out = (float*)d_out;

    ushort_t* ebuf = (ushort_t*)d_ws;                    // 67 MB
    uint_t* QP = (uint_t*)(ebuf + (size_t)B * N * N);    // 8 MB
    uint_t* KP = QP + (size_t)B * N * A;                 // 8 MB
    ushort_t* WqTh = (ushort_t*)(KP + (size_t)B * N * A);
    ushort_t* WqTl = WqTh + H * A;
    ushort_t* WkTh = WqTl + H * A;
    ushort_t* WkTl = WkTh + H * A;
    float* gb = (float*)(WkTl + H * A);                  // 64 KB
    float* lp = gb + (size_t)B * N;                      // 256 KB

    k0_conv<<<(H * A) / 256, 256, 0, stream>>>(Wq, Wk, WqTh, WqTl, WkTh, WkTl);
    k1_mfma<<<(B * N) / 64, 256, 0, stream>>>(x, WqTh, WqTl, WkTh, WkTl,
                                              bq, bk, Wv, bv, QP, KP, gb);
    k2a_mfma<<<B * (N / 128) * 4, 256, 0, stream>>>(QP, KP, ebuf, lp);
    k2b_final<<<4096, 256, 0, stream>>>(ebuf, out, gb, lp);
}